// Round 7
// baseline (143.225 us; speedup 1.0000x reference)
//
#include <hip/hip_runtime.h>
#include <hip/hip_fp16.h>

#define RESOLUTION 0.05f

// native clang vector types — required by __builtin_nontemporal_load/store
typedef float vf2 __attribute__((ext_vector_type(2)));
typedef int   vi2 __attribute__((ext_vector_type(2)));

__device__ __forceinline__ unsigned int pack_h2(float a, float b) {
    __half2 h = __floats2half2_rn(a, b);
    union { __half2 h2; unsigned int ui; } cv; cv.h2 = h;
    return cv.ui;
}
__device__ __forceinline__ float2 unpack_h2(unsigned int u) {
    union { unsigned int ui; __half2 h2; } cv; cv.ui = u;
    return __half22float2(cv.h2);
}

// ---------------- 64B per-voxel record ----------------
// [ float4 meta: cx, cy, cz, 1/size ]
// [ 20 fp16 polynomial coeffs over t^i u^j v^l, 10 uints ]
// sdf(t) = sum c[i][j][l] tx^i ty^j tz^l  (degree<=2 per var) reproduces
//   sum_k w_k(t) * (A_k + Bx_k tx + By_k ty + Bz_k tz),
//   A_k = s_k - B.bits_k, B = size*grad   (delta = size*(t - bits))

__global__ __launch_bounds__(256) void pack_rec_kernel(
    const float* __restrict__ voxel_centers,
    const int*   __restrict__ voxel_sizes,
    const float* __restrict__ sdf_priors,
    const float* __restrict__ grad_priors,
    const int*   __restrict__ vertex_indices, // [V,8]
    uint4*       __restrict__ rec,            // [V*4] : 64B per voxel
    int V)
{
    int v = blockIdx.x * blockDim.x + threadIdx.x;
    if (v >= V) return;

    float size = (float)voxel_sizes[v] * RESOLUTION;
    float cx = voxel_centers[3*v + 0];
    float cy = voxel_centers[3*v + 1];
    float cz = voxel_centers[3*v + 2];

    const int4* vi4 = (const int4*)(vertex_indices + 8*v);
    int4 va = vi4[0];
    int4 vb = vi4[1];
    int vid[8] = {va.x, va.y, va.z, va.w, vb.x, vb.y, vb.z, vb.w};

    float c[3][3][3];
    #pragma unroll
    for (int i = 0; i < 3; ++i)
        #pragma unroll
        for (int j = 0; j < 3; ++j)
            #pragma unroll
            for (int l = 0; l < 3; ++l) c[i][j][l] = 0.0f;

    #pragma unroll
    for (int k = 0; k < 8; ++k) {
        int u = vid[k];
        float s  = sdf_priors[u];
        float Bx = size * grad_priors[3*u + 0];
        float By = size * grad_priors[3*u + 1];
        float Bz = size * grad_priors[3*u + 2];
        int bx = k & 1, by = (k >> 1) & 1, bz = (k >> 2) & 1;
        float A = s - (Bx*(float)bx + By*(float)by + Bz*(float)bz);

        float wx[2] = { bx ? 0.0f : 1.0f, bx ? 1.0f : -1.0f };
        float wy[2] = { by ? 0.0f : 1.0f, by ? 1.0f : -1.0f };
        float wz[2] = { bz ? 0.0f : 1.0f, bz ? 1.0f : -1.0f };

        #pragma unroll
        for (int i = 0; i < 2; ++i)
            #pragma unroll
            for (int j = 0; j < 2; ++j)
                #pragma unroll
                for (int l = 0; l < 2; ++l) {
                    float wc = wx[i] * wy[j] * wz[l];
                    c[i][j][l]     += wc * A;
                    c[i+1][j][l]   += wc * Bx;
                    c[i][j+1][l]   += wc * By;
                    c[i][j][l+1]   += wc * Bz;
                }
    }

    float cf[20];
    #pragma unroll
    for (int l = 0; l < 2; ++l)
        #pragma unroll
        for (int j = 0; j < 2; ++j)
            #pragma unroll
            for (int i = 0; i < 2; ++i) cf[i + 2*j + 4*l] = c[i][j][l];
    #pragma unroll
    for (int l = 0; l < 2; ++l)
        #pragma unroll
        for (int j = 0; j < 2; ++j) {
            cf[8  + j + 2*l] = c[2][j][l];
            cf[12 + j + 2*l] = c[j][2][l];
            cf[16 + j + 2*l] = c[j][l][2];
        }

    union { float f; unsigned int u; } fx, fy, fz, fs;
    fx.f = cx; fy.f = cy; fz.f = cz; fs.f = 1.0f / size;

    uint4* out = rec + 4*v;
    out[0] = make_uint4(fx.u, fy.u, fz.u, fs.u);
    out[1] = make_uint4(pack_h2(cf[0],cf[1]),  pack_h2(cf[2],cf[3]),
                        pack_h2(cf[4],cf[5]),  pack_h2(cf[6],cf[7]));
    out[2] = make_uint4(pack_h2(cf[8],cf[9]),  pack_h2(cf[10],cf[11]),
                        pack_h2(cf[12],cf[13]),pack_h2(cf[14],cf[15]));
    out[3] = make_uint4(pack_h2(cf[16],cf[17]),pack_h2(cf[18],cf[19]), 0u, 0u);
}

__device__ __forceinline__ float eval_poly(const uint4& q1, const uint4& q2,
                                           const uint4& q3, float tx, float ty, float tz)
{
    float2 p01 = unpack_h2(q1.x), p23 = unpack_h2(q1.y);
    float2 p45 = unpack_h2(q1.z), p67 = unpack_h2(q1.w);
    float2 p89 = unpack_h2(q2.x), pab = unpack_h2(q2.y);
    float2 pcd = unpack_h2(q2.z), pef = unpack_h2(q2.w);
    float2 pgh = unpack_h2(q3.x), pij = unpack_h2(q3.y);

    float txty = tx * ty, txtz = tx * tz, tytz = ty * tz;
    float txtytz = txty * tz;

    float s = p01.x + p01.y * tx + p23.x * ty + p23.y * txty
            + p45.x * tz + p45.y * txtz + p67.x * tytz + p67.y * txtytz;
    float tx2 = tx * tx;
    s += tx2 * (p89.x + p89.y * ty + pab.x * tz + pab.y * tytz);
    float ty2 = ty * ty;
    s += ty2 * (pcd.x + pcd.y * tx + pef.x * tz + pef.y * txtz);
    float tz2 = tz * tz;
    s += tz2 * (pgh.x + pgh.y * tx + pij.x * ty + pij.y * txty);
    return s;
}

// ---------- main: 2 points/thread, one gathered line each, nt streaming ----------
__global__ __launch_bounds__(256) void octree_sdf_poly2_kernel(
    const float* __restrict__ points,        // [P,3]
    const int*   __restrict__ voxel_indices, // [P]
    const uint4* __restrict__ rec,           // [V*4]
    float* __restrict__ out_sdf,
    float* __restrict__ out_idx,
    int n)
{
    int t  = blockIdx.x * blockDim.x + threadIdx.x;
    int i0 = 2 * t;
    if (i0 >= n) return;
    bool has2 = (i0 + 1) < n;

    // voxel ids first (gathers depend on them) — 8B-aligned, nt
    int v0, v1;
    if (has2) {
        vi2 vv = __builtin_nontemporal_load((const vi2*)(voxel_indices + i0));
        v0 = vv.x; v1 = vv.y;
    } else {
        v0 = voxel_indices[i0]; v1 = v0;
    }

    // issue all 8 rec-line loads (2 independent 64B lines) up front
    const uint4* r0 = rec + 4 * v0;
    const uint4* r1 = rec + 4 * v1;
    uint4 a0 = r0[0], a1 = r0[1], a2 = r0[2], a3 = r0[3];
    uint4 b0 = r1[0], b1 = r1[1], b2 = r1[2], b3 = r1[3];

    // points: 6 floats at 24t bytes -> 8B-aligned vf2 x3, nt
    float p0x, p0y, p0z, p1x, p1y, p1z;
    if (has2) {
        const vf2* pp = (const vf2*)(points + 3 * i0);
        vf2 u0 = __builtin_nontemporal_load(pp + 0);
        vf2 u1 = __builtin_nontemporal_load(pp + 1);
        vf2 u2 = __builtin_nontemporal_load(pp + 2);
        p0x = u0.x; p0y = u0.y; p0z = u1.x;
        p1x = u1.y; p1y = u2.x; p1z = u2.y;
    } else {
        p0x = points[3*i0+0]; p0y = points[3*i0+1]; p0z = points[3*i0+2];
        p1x = p0x; p1y = p0y; p1z = p0z;
    }

    union { unsigned int u; float f; } m;
    float s0, s1;
    {
        float cx, cy, cz, inv;
        m.u = a0.x; cx = m.f;  m.u = a0.y; cy = m.f;
        m.u = a0.z; cz = m.f;  m.u = a0.w; inv = m.f;
        float tx = (p0x - cx) * inv + 0.5f;
        float ty = (p0y - cy) * inv + 0.5f;
        float tz = (p0z - cz) * inv + 0.5f;
        s0 = eval_poly(a1, a2, a3, tx, ty, tz);
    }
    {
        float cx, cy, cz, inv;
        m.u = b0.x; cx = m.f;  m.u = b0.y; cy = m.f;
        m.u = b0.z; cz = m.f;  m.u = b0.w; inv = m.f;
        float tx = (p1x - cx) * inv + 0.5f;
        float ty = (p1y - cy) * inv + 0.5f;
        float tz = (p1z - cz) * inv + 0.5f;
        s1 = eval_poly(b1, b2, b3, tx, ty, tz);
    }

    if (has2) {
        vf2 os; os.x = s0; os.y = s1;
        vf2 oi; oi.x = (float)v0; oi.y = (float)v1;
        __builtin_nontemporal_store(os, (vf2*)(out_sdf + i0));
        __builtin_nontemporal_store(oi, (vf2*)(out_idx + i0));
    } else {
        out_sdf[i0] = s0;
        out_idx[i0] = (float)v0;
    }
}

// ---------- fallback: direct kernel (no workspace) ----------
__global__ __launch_bounds__(256) void octree_sdf_direct_kernel(
    const float* __restrict__ points,
    const int*   __restrict__ voxel_indices,
    const float* __restrict__ voxel_centers,
    const int*   __restrict__ vertex_indices,
    const int*   __restrict__ voxel_sizes,
    const float* __restrict__ sdf_priors,
    const float* __restrict__ grad_priors,
    float* __restrict__ out_sdf,
    float* __restrict__ out_idx,
    int n)
{
    int i = blockIdx.x * blockDim.x + threadIdx.x;
    if (i >= n) return;

    float px = points[3*i + 0];
    float py = points[3*i + 1];
    float pz = points[3*i + 2];

    int v = voxel_indices[i];

    float cx = voxel_centers[3*v + 0];
    float cy = voxel_centers[3*v + 1];
    float cz = voxel_centers[3*v + 2];
    float size = (float)voxel_sizes[v] * RESOLUTION;

    float tx = (px - cx) / size + 0.5f;
    float ty = (py - cy) / size + 0.5f;
    float tz = (pz - cz) / size + 0.5f;

    const int4* vi4 = (const int4*)(vertex_indices + 8*v);
    int4 va = vi4[0];
    int4 vb = vi4[1];
    int vid[8] = {va.x, va.y, va.z, va.w, vb.x, vb.y, vb.z, vb.w};

    float half_size = 0.5f * size;
    float sdf = 0.0f;

    #pragma unroll
    for (int k = 0; k < 8; ++k) {
        float bx = (float)( k       & 1);
        float by = (float)((k >> 1) & 1);
        float bz = (float)((k >> 2) & 1);

        float w = (bx > 0.0f ? tx : 1.0f - tx)
                * (by > 0.0f ? ty : 1.0f - ty)
                * (bz > 0.0f ? tz : 1.0f - tz);

        int u = vid[k];
        float val = sdf_priors[u];
        float gx  = grad_priors[3*u + 0];
        float gy  = grad_priors[3*u + 1];
        float gz  = grad_priors[3*u + 2];

        float dx = px - (cx + (2.0f*bx - 1.0f) * half_size);
        float dy = py - (cy + (2.0f*by - 1.0f) * half_size);
        float dz = pz - (cz + (2.0f*bz - 1.0f) * half_size);

        sdf += w * (val + gx*dx + gy*dy + gz*dz);
    }

    out_sdf[i] = sdf;
    out_idx[i] = (float)v;
}

extern "C" void kernel_launch(void* const* d_in, const int* in_sizes, int n_in,
                              void* d_out, int out_size, void* d_ws, size_t ws_size,
                              hipStream_t stream) {
    const float* points         = (const float*)d_in[0];
    const int*   voxel_indices  = (const int*)  d_in[1];
    const float* voxel_centers  = (const float*)d_in[2];
    const int*   vertex_indices = (const int*)  d_in[3];
    const int*   voxel_sizes    = (const int*)  d_in[4];
    const float* sdf_priors     = (const float*)d_in[5];
    const float* grad_priors    = (const float*)d_in[6];

    int n = in_sizes[1];  // points
    int V = in_sizes[4];  // voxels
    float* out_sdf = (float*)d_out;
    float* out_idx = out_sdf + n;

    int block = 256;
    int gridV = (V + block - 1) / block;

    size_t need = (size_t)V * 64;

    if (ws_size >= need) {
        uint4* rec = (uint4*)d_ws;

        pack_rec_kernel<<<gridV, block, 0, stream>>>(
            voxel_centers, voxel_sizes, sdf_priors, grad_priors, vertex_indices,
            rec, V);

        int nt = (n + 1) / 2;                       // threads (2 points each)
        int gridP = (nt + block - 1) / block;
        octree_sdf_poly2_kernel<<<gridP, block, 0, stream>>>(
            points, voxel_indices, rec, out_sdf, out_idx, n);
    } else {
        int gridP = (n + block - 1) / block;
        octree_sdf_direct_kernel<<<gridP, block, 0, stream>>>(
            points, voxel_indices, voxel_centers, vertex_indices,
            voxel_sizes, sdf_priors, grad_priors, out_sdf, out_idx, n);
    }
}

// Round 8
// 141.487 us; speedup vs baseline: 1.0123x; 1.0123x over previous
//
#include <hip/hip_runtime.h>
#include <hip/hip_fp16.h>

#define RESOLUTION 0.05f

__device__ __forceinline__ unsigned int pack_h2(float a, float b) {
    __half2 h = __floats2half2_rn(a, b);
    union { __half2 h2; unsigned int ui; } cv; cv.h2 = h;
    return cv.ui;
}
__device__ __forceinline__ float2 unpack_h2(unsigned int u) {
    union { unsigned int ui; __half2 h2; } cv; cv.ui = u;
    return __half22float2(cv.h2);
}

// ---------------- 64B per-voxel record ----------------
// [ float4 meta: cx, cy, cz, 1/size ]
// [ 20 fp16 polynomial coeffs over t^i t^j t^l (deg<=2/var), 10 uints ]
// sdf(t) = sum c[i][j][l] tx^i ty^j tz^l  reproduces
//   sum_k w_k(t) * (A_k + Bx_k tx + By_k ty + Bz_k tz),
//   A_k = s_k - B.bits_k, B = size*grad   (delta = size*(t - bits))

__global__ __launch_bounds__(256) void pack_rec_kernel(
    const float* __restrict__ voxel_centers,
    const int*   __restrict__ voxel_sizes,
    const float* __restrict__ sdf_priors,
    const float* __restrict__ grad_priors,
    const int*   __restrict__ vertex_indices, // [V,8]
    uint4*       __restrict__ rec,            // [V*4] : 64B per voxel
    int V)
{
    int v = blockIdx.x * blockDim.x + threadIdx.x;
    if (v >= V) return;

    float size = (float)voxel_sizes[v] * RESOLUTION;
    float cx = voxel_centers[3*v + 0];
    float cy = voxel_centers[3*v + 1];
    float cz = voxel_centers[3*v + 2];

    const int4* vi4 = (const int4*)(vertex_indices + 8*v);
    int4 va = vi4[0];
    int4 vb = vi4[1];
    int vid[8] = {va.x, va.y, va.z, va.w, vb.x, vb.y, vb.z, vb.w};

    float c[3][3][3];
    #pragma unroll
    for (int i = 0; i < 3; ++i)
        #pragma unroll
        for (int j = 0; j < 3; ++j)
            #pragma unroll
            for (int l = 0; l < 3; ++l) c[i][j][l] = 0.0f;

    #pragma unroll
    for (int k = 0; k < 8; ++k) {
        int u = vid[k];
        float s  = sdf_priors[u];
        float Bx = size * grad_priors[3*u + 0];
        float By = size * grad_priors[3*u + 1];
        float Bz = size * grad_priors[3*u + 2];
        int bx = k & 1, by = (k >> 1) & 1, bz = (k >> 2) & 1;
        float A = s - (Bx*(float)bx + By*(float)by + Bz*(float)bz);

        float wx[2] = { bx ? 0.0f : 1.0f, bx ? 1.0f : -1.0f };
        float wy[2] = { by ? 0.0f : 1.0f, by ? 1.0f : -1.0f };
        float wz[2] = { bz ? 0.0f : 1.0f, bz ? 1.0f : -1.0f };

        #pragma unroll
        for (int i = 0; i < 2; ++i)
            #pragma unroll
            for (int j = 0; j < 2; ++j)
                #pragma unroll
                for (int l = 0; l < 2; ++l) {
                    float wc = wx[i] * wy[j] * wz[l];
                    c[i][j][l]     += wc * A;
                    c[i+1][j][l]   += wc * Bx;
                    c[i][j+1][l]   += wc * By;
                    c[i][j][l+1]   += wc * Bz;
                }
    }

    float cf[20];
    #pragma unroll
    for (int l = 0; l < 2; ++l)
        #pragma unroll
        for (int j = 0; j < 2; ++j)
            #pragma unroll
            for (int i = 0; i < 2; ++i) cf[i + 2*j + 4*l] = c[i][j][l];
    #pragma unroll
    for (int l = 0; l < 2; ++l)
        #pragma unroll
        for (int j = 0; j < 2; ++j) {
            cf[8  + j + 2*l] = c[2][j][l];
            cf[12 + j + 2*l] = c[j][2][l];
            cf[16 + j + 2*l] = c[j][l][2];
        }

    union { float f; unsigned int u; } fx, fy, fz, fs;
    fx.f = cx; fy.f = cy; fz.f = cz; fs.f = 1.0f / size;

    uint4* out = rec + 4*v;
    out[0] = make_uint4(fx.u, fy.u, fz.u, fs.u);
    out[1] = make_uint4(pack_h2(cf[0],cf[1]),  pack_h2(cf[2],cf[3]),
                        pack_h2(cf[4],cf[5]),  pack_h2(cf[6],cf[7]));
    out[2] = make_uint4(pack_h2(cf[8],cf[9]),  pack_h2(cf[10],cf[11]),
                        pack_h2(cf[12],cf[13]),pack_h2(cf[14],cf[15]));
    out[3] = make_uint4(pack_h2(cf[16],cf[17]),pack_h2(cf[18],cf[19]), 0u, 0u);
}

// ---------- main: 1 point/thread, one gathered line, nt streaming ----------
__global__ __launch_bounds__(256) void octree_sdf_poly_kernel(
    const float* __restrict__ points,        // [P,3]
    const int*   __restrict__ voxel_indices, // [P]
    const uint4* __restrict__ rec,           // [V*4]
    float* __restrict__ out_sdf,
    float* __restrict__ out_idx,
    int n)
{
    int i = blockIdx.x * blockDim.x + threadIdx.x;
    if (i >= n) return;

    // stream loads with nt hint: read-once, don't pollute L2 (rec table lives there)
    int v = __builtin_nontemporal_load(voxel_indices + i);

    const uint4* r = rec + 4*v;
    uint4 q0 = r[0], q1 = r[1], q2 = r[2], q3 = r[3];

    float px = __builtin_nontemporal_load(points + 3*i + 0);
    float py = __builtin_nontemporal_load(points + 3*i + 1);
    float pz = __builtin_nontemporal_load(points + 3*i + 2);

    union { unsigned int u; float f; } m0, m1, m2, m3;
    m0.u = q0.x; m1.u = q0.y; m2.u = q0.z; m3.u = q0.w;

    float tx = (px - m0.f) * m3.f + 0.5f;
    float ty = (py - m1.f) * m3.f + 0.5f;
    float tz = (pz - m2.f) * m3.f + 0.5f;

    float2 p01 = unpack_h2(q1.x), p23 = unpack_h2(q1.y);
    float2 p45 = unpack_h2(q1.z), p67 = unpack_h2(q1.w);
    float2 p89 = unpack_h2(q2.x), pab = unpack_h2(q2.y);
    float2 pcd = unpack_h2(q2.z), pef = unpack_h2(q2.w);
    float2 pgh = unpack_h2(q3.x), pij = unpack_h2(q3.y);

    float txty = tx * ty, txtz = tx * tz, tytz = ty * tz;
    float txtytz = txty * tz;

    float s = p01.x + p01.y * tx + p23.x * ty + p23.y * txty
            + p45.x * tz + p45.y * txtz + p67.x * tytz + p67.y * txtytz;
    float tx2 = tx * tx;
    s += tx2 * (p89.x + p89.y * ty + pab.x * tz + pab.y * tytz);
    float ty2 = ty * ty;
    s += ty2 * (pcd.x + pcd.y * tx + pef.x * tz + pef.y * txtz);
    float tz2 = tz * tz;
    s += tz2 * (pgh.x + pgh.y * tx + pij.x * ty + pij.y * txty);

    __builtin_nontemporal_store(s, out_sdf + i);
    __builtin_nontemporal_store((float)v, out_idx + i);
}

// ---------- fallback: direct kernel (no workspace) ----------
__global__ __launch_bounds__(256) void octree_sdf_direct_kernel(
    const float* __restrict__ points,
    const int*   __restrict__ voxel_indices,
    const float* __restrict__ voxel_centers,
    const int*   __restrict__ vertex_indices,
    const int*   __restrict__ voxel_sizes,
    const float* __restrict__ sdf_priors,
    const float* __restrict__ grad_priors,
    float* __restrict__ out_sdf,
    float* __restrict__ out_idx,
    int n)
{
    int i = blockIdx.x * blockDim.x + threadIdx.x;
    if (i >= n) return;

    float px = points[3*i + 0];
    float py = points[3*i + 1];
    float pz = points[3*i + 2];

    int v = voxel_indices[i];

    float cx = voxel_centers[3*v + 0];
    float cy = voxel_centers[3*v + 1];
    float cz = voxel_centers[3*v + 2];
    float size = (float)voxel_sizes[v] * RESOLUTION;

    float tx = (px - cx) / size + 0.5f;
    float ty = (py - cy) / size + 0.5f;
    float tz = (pz - cz) / size + 0.5f;

    const int4* vi4 = (const int4*)(vertex_indices + 8*v);
    int4 va = vi4[0];
    int4 vb = vi4[1];
    int vid[8] = {va.x, va.y, va.z, va.w, vb.x, vb.y, vb.z, vb.w};

    float half_size = 0.5f * size;
    float sdf = 0.0f;

    #pragma unroll
    for (int k = 0; k < 8; ++k) {
        float bx = (float)( k       & 1);
        float by = (float)((k >> 1) & 1);
        float bz = (float)((k >> 2) & 1);

        float w = (bx > 0.0f ? tx : 1.0f - tx)
                * (by > 0.0f ? ty : 1.0f - ty)
                * (bz > 0.0f ? tz : 1.0f - tz);

        int u = vid[k];
        float val = sdf_priors[u];
        float gx  = grad_priors[3*u + 0];
        float gy  = grad_priors[3*u + 1];
        float gz  = grad_priors[3*u + 2];

        float dx = px - (cx + (2.0f*bx - 1.0f) * half_size);
        float dy = py - (cy + (2.0f*by - 1.0f) * half_size);
        float dz = pz - (cz + (2.0f*bz - 1.0f) * half_size);

        sdf += w * (val + gx*dx + gy*dy + gz*dz);
    }

    out_sdf[i] = sdf;
    out_idx[i] = (float)v;
}

extern "C" void kernel_launch(void* const* d_in, const int* in_sizes, int n_in,
                              void* d_out, int out_size, void* d_ws, size_t ws_size,
                              hipStream_t stream) {
    const float* points         = (const float*)d_in[0];
    const int*   voxel_indices  = (const int*)  d_in[1];
    const float* voxel_centers  = (const float*)d_in[2];
    const int*   vertex_indices = (const int*)  d_in[3];
    const int*   voxel_sizes    = (const int*)  d_in[4];
    const float* sdf_priors     = (const float*)d_in[5];
    const float* grad_priors    = (const float*)d_in[6];

    int n = in_sizes[1];  // points
    int V = in_sizes[4];  // voxels
    float* out_sdf = (float*)d_out;
    float* out_idx = out_sdf + n;

    int block = 256;
    int gridV = (V + block - 1) / block;
    int gridP = (n + block - 1) / block;

    size_t need = (size_t)V * 64;

    if (ws_size >= need) {
        uint4* rec = (uint4*)d_ws;

        pack_rec_kernel<<<gridV, block, 0, stream>>>(
            voxel_centers, voxel_sizes, sdf_priors, grad_priors, vertex_indices,
            rec, V);

        octree_sdf_poly_kernel<<<gridP, block, 0, stream>>>(
            points, voxel_indices, rec, out_sdf, out_idx, n);
    } else {
        octree_sdf_direct_kernel<<<gridP, block, 0, stream>>>(
            points, voxel_indices, voxel_centers, vertex_indices,
            voxel_sizes, sdf_priors, grad_priors, out_sdf, out_idx, n);
    }
}